// Round 1
// baseline (223.879 us; speedup 1.0000x reference)
//
#include <hip/hip_runtime.h>
#include <stdint.h>

#define N 1024
#define BATCH 32

// ---------------------------------------------------------------------------
// Kernel 1: per-row soft-rank. One block (256 threads) per batch row.
//   1) build 64-bit sortable keys, counting-sort positions (descending, stable)
//   2) thread 0: PAV non-increasing isotonic regression of y[i]=s[i]-(N-i)
//   3) ranks[j] = x[j] - sol[pos[j]]
// ---------------------------------------------------------------------------
__global__ __launch_bounds__(256) void ranks_kernel(const float* __restrict__ x,
                                                    float* __restrict__ ranks) {
    __shared__ uint64_t keys[N];     // 8 KB
    __shared__ float    ss[N];       // sorted values (descending)      4 KB
    __shared__ float    yv[N];       // y = s - (N-i) + 512 (centered)  4 KB
    __shared__ float    sol[N];      // isotonic solution (centered)    4 KB
    __shared__ float    stk_sum[N];  // PAV stack                       4 KB
    __shared__ int      stk_cnt[N];  //                                 4 KB

    const int b = blockIdx.x;
    const int t = threadIdx.x;
    const int j0 = t << 2;

    // ---- load row, build sortable keys ------------------------------------
    const float4 xq = reinterpret_cast<const float4*>(x + b * N)[t];
    {
        const float vv[4] = {xq.x, xq.y, xq.z, xq.w};
        #pragma unroll
        for (int e = 0; e < 4; ++e) {
            uint32_t u = __float_as_uint(vv[e]);
            // monotone float->uint transform (ascending)
            u ^= (u & 0x80000000u) ? 0xFFFFFFFFu : 0x80000000u;
            // descending sort, stable (index asc) => count keys strictly greater
            keys[j0 + e] = (((uint64_t)u) << 10) | (uint64_t)(1023 - (j0 + e));
        }
    }
    __syncthreads();

    // ---- counting positions: p = #{k : key_k > key_j} ---------------------
    const uint64_t k0 = keys[j0 + 0];
    const uint64_t k1 = keys[j0 + 1];
    const uint64_t k2 = keys[j0 + 2];
    const uint64_t k3 = keys[j0 + 3];
    int c0 = 0, c1 = 0, c2 = 0, c3 = 0;
    for (int k = 0; k < N; k += 2) {
        // 16B LDS read, same address across lanes -> broadcast
        const uint64_t ka = keys[k];
        const uint64_t kb = keys[k + 1];
        c0 += (ka > k0); c1 += (ka > k1); c2 += (ka > k2); c3 += (ka > k3);
        c0 += (kb > k0); c1 += (kb > k1); c2 += (kb > k2); c3 += (kb > k3);
    }
    // scatter values into sorted order (positions are a permutation)
    ss[c0] = xq.x; ss[c1] = xq.y; ss[c2] = xq.z; ss[c3] = xq.w;
    __syncthreads();

    // ---- y[i] = s[i] - (N - i) + 512 (centered for fp32 precision) --------
    {
        const float4 sq = reinterpret_cast<const float4*>(ss)[t];
        float4 yq;
        yq.x = sq.x + (float)(j0 + 0 - 512);
        yq.y = sq.y + (float)(j0 + 1 - 512);
        yq.z = sq.z + (float)(j0 + 2 - 512);
        yq.w = sq.w + (float)(j0 + 3 - 512);
        reinterpret_cast<float4*>(yv)[t] = yq;
    }
    __syncthreads();

    // ---- PAV (non-increasing), thread 0 -----------------------------------
    if (t == 0) {
        float sumT = yv[0];  int cntT = 1;   // top block (registers)
        float sumP = 0.0f;   int cntP = 0;   // block below top (registers)
        int sp = 0;                          // deeper stack in LDS

        for (int base = 0; base < N; base += 8) {
            const float4 a = *reinterpret_cast<const float4*>(&yv[base]);
            const float4 bq = *reinterpret_cast<const float4*>(&yv[base + 4]);
            const float yb[8] = {a.x, a.y, a.z, a.w, bq.x, bq.y, bq.z, bq.w};
            #pragma unroll
            for (int e = 0; e < 8; ++e) {
                if (base + e == 0) continue;
                const float v = yb[e];
                if (v * (float)cntT > sumT) {          // mean(new) > mean(top): merge
                    sumT += v; cntT += 1;
                    while (cntP > 0 && sumT * (float)cntP > sumP * (float)cntT) {
                        sumT += sumP; cntT += cntP;
                        if (sp > 0) { --sp; sumP = stk_sum[sp]; cntP = stk_cnt[sp]; }
                        else        { cntP = 0; }
                    }
                } else {                               // push new block
                    if (cntP > 0) { stk_sum[sp] = sumP; stk_cnt[sp] = cntP; ++sp; }
                    sumP = sumT; cntP = cntT;
                    sumT = v;    cntT = 1;
                }
            }
        }
        // emit solution, bottom -> top
        int pos = 0;
        for (int e = 0; e < sp; ++e) {
            const float m = stk_sum[e] / (float)stk_cnt[e];
            for (int c = 0; c < stk_cnt[e]; ++c) sol[pos++] = m;
        }
        if (cntP > 0) {
            const float m = sumP / (float)cntP;
            for (int c = 0; c < cntP; ++c) sol[pos++] = m;
        }
        {
            const float m = sumT / (float)cntT;
            for (int c = 0; c < cntT; ++c) sol[pos++] = m;
        }
    }
    __syncthreads();

    // ---- ranks[j] = x[j] - (sol[p_j] - 512) -------------------------------
    float4 r;
    r.x = xq.x - sol[c0] + 512.0f;
    r.y = xq.y - sol[c1] + 512.0f;
    r.z = xq.z - sol[c2] + 512.0f;
    r.w = xq.w - sol[c3] + 512.0f;
    reinterpret_cast<float4*>(ranks + b * N)[t] = r;
}

// ---------------------------------------------------------------------------
// Kernel 2: out[b,j,i] = relu(1 - |ranks[b,j] - (i+1)|)
// One block per (b,j) row; 256 threads x float4 = 1024 elements.
// ---------------------------------------------------------------------------
__global__ __launch_bounds__(256) void fill_kernel(const float* __restrict__ ranks,
                                                   float* __restrict__ out) {
    const int row = blockIdx.x;            // b*N + j
    const float r = ranks[row];
    const int i = threadIdx.x << 2;
    float4 o;
    o.x = fmaxf(1.0f - fabsf(r - (float)(i + 1)), 0.0f);
    o.y = fmaxf(1.0f - fabsf(r - (float)(i + 2)), 0.0f);
    o.z = fmaxf(1.0f - fabsf(r - (float)(i + 3)), 0.0f);
    o.w = fmaxf(1.0f - fabsf(r - (float)(i + 4)), 0.0f);
    reinterpret_cast<float4*>(out + (size_t)row * N)[threadIdx.x] = o;
}

extern "C" void kernel_launch(void* const* d_in, const int* in_sizes, int n_in,
                              void* d_out, int out_size, void* d_ws, size_t ws_size,
                              hipStream_t stream) {
    const float* x = (const float*)d_in[0];
    float* out = (float*)d_out;
    float* ranks = (float*)d_ws;           // 32*1024 floats = 128 KB scratch

    ranks_kernel<<<BATCH, 256, 0, stream>>>(x, ranks);
    fill_kernel<<<BATCH * N, 256, 0, stream>>>(ranks, out);
}

// Round 3
// 163.418 us; speedup vs baseline: 1.3700x; 1.3700x over previous
//
#include <hip/hip_runtime.h>
#include <stdint.h>

#define N 1024
#define BATCH 32

typedef float nfloat4 __attribute__((ext_vector_type(4)));

// ---------------------------------------------------------------------------
// Kernel 1: per-row soft-rank. One block (256 threads) per batch row.
//   1) 64-bit sortable keys, counting-sort positions (descending, stable)
//   2) pre-pool non-descending runs in parallel (PAV boundaries only at
//      strict descents y[i-1] > y[i]); scan for seg-ids + double prefix sums
//   3) thread 0: PAV over the (few) runs
//   4) ranks[j] = x[j] - sol[pos[j]]
// ---------------------------------------------------------------------------
__global__ __launch_bounds__(256) void ranks_kernel(const float* __restrict__ x,
                                                    float* __restrict__ ranks) {
    __shared__ uint64_t keys[N];        // 8 KB; reused as PAV double stack
    __shared__ float    ss[N];          // sorted values (descending)
    __shared__ float    yv[N];          // y = s + (i - 512)  (centered)
    __shared__ double   csum[N];        // inclusive prefix of yv (double)
    __shared__ int      segid[N];       // run id per sorted position
    __shared__ int      run_start[N+1]; // run boundary positions
    __shared__ float    run_mean[N];    // final (centered) mean per run
    __shared__ int      stk_cnt[N];     // PAV stack: element counts
    __shared__ int      stk_runs[N];    // PAV stack: runs per block
    __shared__ double   wsumD[4];
    __shared__ int      wsumI[4];

    const int b = blockIdx.x;
    const int t = threadIdx.x;
    const int j0 = t << 2;
    const int lane = t & 63;
    const int wid = t >> 6;

    // ---- load row, build sortable keys ------------------------------------
    const float4 xq = reinterpret_cast<const float4*>(x + b * N)[t];
    {
        const float vv[4] = {xq.x, xq.y, xq.z, xq.w};
        #pragma unroll
        for (int e = 0; e < 4; ++e) {
            uint32_t u = __float_as_uint(vv[e]);
            u ^= (u & 0x80000000u) ? 0xFFFFFFFFu : 0x80000000u;  // monotone map
            // descending, stable: count keys strictly greater
            keys[j0 + e] = (((uint64_t)u) << 10) | (uint64_t)(1023 - (j0 + e));
        }
    }
    __syncthreads();

    // ---- counting positions: p = #{k : key_k > key_j} ---------------------
    const uint64_t k0 = keys[j0 + 0];
    const uint64_t k1 = keys[j0 + 1];
    const uint64_t k2 = keys[j0 + 2];
    const uint64_t k3 = keys[j0 + 3];
    int c0 = 0, c1 = 0, c2 = 0, c3 = 0;
    for (int k = 0; k < N; k += 2) {
        const uint64_t ka = keys[k];
        const uint64_t kb = keys[k + 1];
        c0 += (ka > k0); c1 += (ka > k1); c2 += (ka > k2); c3 += (ka > k3);
        c0 += (kb > k0); c1 += (kb > k1); c2 += (kb > k2); c3 += (kb > k3);
    }
    ss[c0] = xq.x; ss[c1] = xq.y; ss[c2] = xq.z; ss[c3] = xq.w;
    __syncthreads();

    // ---- y[i] = s[i] + (i - 512)  (centered for precision) ----------------
    float4 yq;
    {
        const float4 sq = reinterpret_cast<const float4*>(ss)[t];
        yq.x = sq.x + (float)(j0 - 512);
        yq.y = sq.y + (float)(j0 - 511);
        yq.z = sq.z + (float)(j0 - 510);
        yq.w = sq.w + (float)(j0 - 509);
        reinterpret_cast<float4*>(yv)[t] = yq;
    }
    __syncthreads();

    // ---- descent flags + thread-local inclusive scans ---------------------
    const float ye[4] = {yq.x, yq.y, yq.z, yq.w};
    int    fl[4];          // raw flags
    int    lf[4];          // local inclusive flag scan
    double lys[4];         // local inclusive y scan
    {
        float prev = (j0 == 0) ? -1.0e30f : yv[j0 - 1];
        double accy = 0.0; int accf = 0;
        #pragma unroll
        for (int e = 0; e < 4; ++e) {
            const int f = (prev > ye[e]) ? 1 : 0;   // strict descent = run start
            prev = ye[e];
            fl[e] = f;
            accf += f;           lf[e]  = accf;
            accy += (double)ye[e]; lys[e] = accy;
        }
    }
    // ---- wave-level inclusive scan of thread totals -----------------------
    double vy = lys[3]; int vf = lf[3];
    #pragma unroll
    for (int off = 1; off < 64; off <<= 1) {
        const double oy = __shfl_up(vy, off);
        const int    of = __shfl_up(vf, off);
        if (lane >= off) { vy += oy; vf += of; }
    }
    if (lane == 63) { wsumD[wid] = vy; wsumI[wid] = vf; }
    __syncthreads();
    // ---- cross-wave offsets, per-element inclusive values -----------------
    {
        double basey = vy - lys[3]; int basef = vf - lf[3];
        for (int w = 0; w < wid; ++w) { basey += wsumD[w]; basef += wsumI[w]; }
        #pragma unroll
        for (int e = 0; e < 4; ++e) {
            const int p   = j0 + e;
            const int seg = basef + lf[e];
            segid[p] = seg;
            csum[p]  = basey + lys[e];
            if (fl[e]) run_start[seg] = p;   // unique writer per seg >= 1
        }
        if (t == 0) run_start[0] = 0;
    }
    __syncthreads();

    // ---- PAV over runs (thread 0; R is tiny for near-monotone y) ----------
    if (t == 0) {
        const int R = segid[N - 1] + 1;
        run_start[R] = N;
        double* stk_sum = reinterpret_cast<double*>(keys);  // reuse keys LDS
        int sp = 0;
        for (int r = 0; r < R; ++r) {
            const int a   = run_start[r];
            const int bnd = run_start[r + 1];
            double s = csum[bnd - 1] - ((a > 0) ? csum[a - 1] : 0.0);
            int    c = bnd - a;
            int    nr = 1;
            // pool while top block's mean < new block's mean
            while (sp > 0 && s * (double)stk_cnt[sp - 1] > stk_sum[sp - 1] * (double)c) {
                s  += stk_sum[sp - 1];
                c  += stk_cnt[sp - 1];
                nr += stk_runs[sp - 1];
                --sp;
            }
            stk_sum[sp] = s; stk_cnt[sp] = c; stk_runs[sp] = nr; ++sp;
        }
        int rc = 0;
        for (int e2 = 0; e2 < sp; ++e2) {
            const float m = (float)(stk_sum[e2] / (double)stk_cnt[e2]);
            for (int q = 0; q < stk_runs[e2]; ++q) run_mean[rc++] = m;
        }
    }
    __syncthreads();

    // ---- ranks[j] = x[j] - (sol - 512) ------------------------------------
    float4 r4;
    r4.x = xq.x - run_mean[segid[c0]] + 512.0f;
    r4.y = xq.y - run_mean[segid[c1]] + 512.0f;
    r4.z = xq.z - run_mean[segid[c2]] + 512.0f;
    r4.w = xq.w - run_mean[segid[c3]] + 512.0f;
    reinterpret_cast<float4*>(ranks + b * N)[t] = r4;
}

// ---------------------------------------------------------------------------
// Kernel 2: out[b,j,i] = relu(1 - |ranks[b,j] - (i+1)|)
// One block per (b,j) row; 256 threads x float4 = 1024 elements.
// ---------------------------------------------------------------------------
__global__ __launch_bounds__(256) void fill_kernel(const float* __restrict__ ranks,
                                                   float* __restrict__ out) {
    const int row = blockIdx.x;            // b*N + j
    const float r = ranks[row];
    const int i = threadIdx.x << 2;
    nfloat4 o;
    o.x = fmaxf(1.0f - fabsf(r - (float)(i + 1)), 0.0f);
    o.y = fmaxf(1.0f - fabsf(r - (float)(i + 2)), 0.0f);
    o.z = fmaxf(1.0f - fabsf(r - (float)(i + 3)), 0.0f);
    o.w = fmaxf(1.0f - fabsf(r - (float)(i + 4)), 0.0f);
    __builtin_nontemporal_store(o, reinterpret_cast<nfloat4*>(out + (size_t)row * N) + threadIdx.x);
}

extern "C" void kernel_launch(void* const* d_in, const int* in_sizes, int n_in,
                              void* d_out, int out_size, void* d_ws, size_t ws_size,
                              hipStream_t stream) {
    const float* x = (const float*)d_in[0];
    float* out = (float*)d_out;
    float* ranks = (float*)d_ws;           // 32*1024 floats = 128 KB scratch

    ranks_kernel<<<BATCH, 256, 0, stream>>>(x, ranks);
    fill_kernel<<<BATCH * N, 256, 0, stream>>>(ranks, out);
}

// Round 4
// 147.775 us; speedup vs baseline: 1.5150x; 1.1059x over previous
//
#include <hip/hip_runtime.h>
#include <stdint.h>

#define N 1024
#define BATCH 32

typedef float nfloat4 __attribute__((ext_vector_type(4)));

// ---------------------------------------------------------------------------
// Kernel A: counting-sort positions. 8 blocks per row, 256 threads each.
//   Each block builds all 1024 keys (redundant, cheap), then counts the
//   descending-stable sort position of its 128 assigned elements.
//   2 threads per element, each covering half of the key range.
// ---------------------------------------------------------------------------
__global__ __launch_bounds__(256) void count_kernel(const float* __restrict__ x,
                                                    int* __restrict__ pos_g) {
    __shared__ uint64_t keys[N];      // 8 KB
    __shared__ int      partial[256]; // 1 KB

    const int row   = blockIdx.x >> 3;
    const int chunk = blockIdx.x & 7;
    const int t     = threadIdx.x;

    // ---- build all keys for this row --------------------------------------
    const float4 xq = reinterpret_cast<const float4*>(x + row * N)[t];
    {
        const float vv[4] = {xq.x, xq.y, xq.z, xq.w};
        const int j0 = t << 2;
        #pragma unroll
        for (int e = 0; e < 4; ++e) {
            uint32_t u = __float_as_uint(vv[e]);
            u ^= (u & 0x80000000u) ? 0xFFFFFFFFu : 0x80000000u;  // monotone map
            // descending, stable: position = #{k : key_k > key_j}
            keys[j0 + e] = (((uint64_t)u) << 10) | (uint64_t)(1023 - (j0 + e));
        }
    }
    __syncthreads();

    // ---- count: element e over key half [half*512, half*512+512) ----------
    const int e    = (chunk << 7) + (t & 127);
    const int half = t >> 7;                 // wave-uniform (waves 0,1 vs 2,3)
    const uint64_t kk = keys[e];
    const int kbeg = half << 9;
    int c = 0;
    for (int k = kbeg; k < kbeg + 512; k += 4) {
        c += (int)(keys[k    ] > kk);
        c += (int)(keys[k + 1] > kk);
        c += (int)(keys[k + 2] > kk);
        c += (int)(keys[k + 3] > kk);
    }
    partial[t] = c;
    __syncthreads();

    if (t < 128) pos_g[row * N + e] = partial[t] + partial[t + 128];
}

// ---------------------------------------------------------------------------
// Kernel B: per-row soft-rank from positions. One block per row.
//   LDS scatter to sorted order, parallel run-pooling scan, tiny serial PAV
//   over runs, rank emit.
// ---------------------------------------------------------------------------
__global__ __launch_bounds__(256) void ranks_kernel(const float* __restrict__ x,
                                                    const int* __restrict__ pos_g,
                                                    float* __restrict__ ranks) {
    __shared__ float    ss[N];          // sorted values (descending)
    __shared__ float    yv[N];          // y = s + (i - 512)  (centered)
    __shared__ double   csum[N];        // inclusive prefix of yv (double)
    __shared__ int      segid[N];       // run id per sorted position
    __shared__ int      run_start[N+1]; // run boundary positions
    __shared__ float    run_mean[N];    // final (centered) mean per run
    __shared__ double   stk_sum[N];     // PAV stack: block sums
    __shared__ int      stk_cnt[N];     // PAV stack: element counts
    __shared__ int      stk_runs[N];    // PAV stack: runs per block
    __shared__ double   wsumD[4];
    __shared__ int      wsumI[4];

    const int b = blockIdx.x;
    const int t = threadIdx.x;
    const int j0 = t << 2;
    const int lane = t & 63;
    const int wid = t >> 6;

    // ---- load row + positions, scatter into sorted order ------------------
    const float4 xq = reinterpret_cast<const float4*>(x + b * N)[t];
    const int4   pq = reinterpret_cast<const int4*>(pos_g + b * N)[t];
    ss[pq.x] = xq.x; ss[pq.y] = xq.y; ss[pq.z] = xq.z; ss[pq.w] = xq.w;
    __syncthreads();

    // ---- y[i] = s[i] + (i - 512)  (centered for precision) ----------------
    float4 yq;
    {
        const float4 sq = reinterpret_cast<const float4*>(ss)[t];
        yq.x = sq.x + (float)(j0 - 512);
        yq.y = sq.y + (float)(j0 - 511);
        yq.z = sq.z + (float)(j0 - 510);
        yq.w = sq.w + (float)(j0 - 509);
        reinterpret_cast<float4*>(yv)[t] = yq;
    }
    __syncthreads();

    // ---- descent flags + thread-local inclusive scans ---------------------
    const float ye[4] = {yq.x, yq.y, yq.z, yq.w};
    int    fl[4];          // raw flags
    int    lf[4];          // local inclusive flag scan
    double lys[4];         // local inclusive y scan
    {
        float prev = (j0 == 0) ? -1.0e30f : yv[j0 - 1];
        double accy = 0.0; int accf = 0;
        #pragma unroll
        for (int e = 0; e < 4; ++e) {
            const int f = (prev > ye[e]) ? 1 : 0;   // strict descent = run start
            prev = ye[e];
            fl[e] = f;
            accf += f;             lf[e]  = accf;
            accy += (double)ye[e]; lys[e] = accy;
        }
    }
    // ---- wave-level inclusive scan of thread totals -----------------------
    double vy = lys[3]; int vf = lf[3];
    #pragma unroll
    for (int off = 1; off < 64; off <<= 1) {
        const double oy = __shfl_up(vy, off);
        const int    of = __shfl_up(vf, off);
        if (lane >= off) { vy += oy; vf += of; }
    }
    if (lane == 63) { wsumD[wid] = vy; wsumI[wid] = vf; }
    __syncthreads();
    // ---- cross-wave offsets, per-element inclusive values -----------------
    {
        double basey = vy - lys[3]; int basef = vf - lf[3];
        for (int w = 0; w < wid; ++w) { basey += wsumD[w]; basef += wsumI[w]; }
        #pragma unroll
        for (int e = 0; e < 4; ++e) {
            const int p   = j0 + e;
            const int seg = basef + lf[e];
            segid[p] = seg;
            csum[p]  = basey + lys[e];
            if (fl[e]) run_start[seg] = p;   // unique writer per seg >= 1
        }
        if (t == 0) run_start[0] = 0;
    }
    __syncthreads();

    // ---- PAV over runs (thread 0; R is tiny for near-monotone y) ----------
    if (t == 0) {
        const int R = segid[N - 1] + 1;
        run_start[R] = N;
        int sp = 0;
        for (int r = 0; r < R; ++r) {
            const int a   = run_start[r];
            const int bnd = run_start[r + 1];
            double s = csum[bnd - 1] - ((a > 0) ? csum[a - 1] : 0.0);
            int    c = bnd - a;
            int    nr = 1;
            // pool while top block's mean < new block's mean
            while (sp > 0 && s * (double)stk_cnt[sp - 1] > stk_sum[sp - 1] * (double)c) {
                s  += stk_sum[sp - 1];
                c  += stk_cnt[sp - 1];
                nr += stk_runs[sp - 1];
                --sp;
            }
            stk_sum[sp] = s; stk_cnt[sp] = c; stk_runs[sp] = nr; ++sp;
        }
        int rc = 0;
        for (int e2 = 0; e2 < sp; ++e2) {
            const float m = (float)(stk_sum[e2] / (double)stk_cnt[e2]);
            for (int q = 0; q < stk_runs[e2]; ++q) run_mean[rc++] = m;
        }
    }
    __syncthreads();

    // ---- ranks[j] = x[j] - (sol - 512) ------------------------------------
    float4 r4;
    r4.x = xq.x - run_mean[segid[pq.x]] + 512.0f;
    r4.y = xq.y - run_mean[segid[pq.y]] + 512.0f;
    r4.z = xq.z - run_mean[segid[pq.z]] + 512.0f;
    r4.w = xq.w - run_mean[segid[pq.w]] + 512.0f;
    reinterpret_cast<float4*>(ranks + b * N)[t] = r4;
}

// ---------------------------------------------------------------------------
// Kernel C: out[b,j,i] = relu(1 - |ranks[b,j] - (i+1)|)
// 4 rows per block; 256 threads x float4 = 1024 elements per row.
// ---------------------------------------------------------------------------
__global__ __launch_bounds__(256) void fill_kernel(const float* __restrict__ ranks,
                                                   float* __restrict__ out) {
    const int r0 = blockIdx.x << 2;        // first row (b*N + j)
    const int i = threadIdx.x << 2;
    // hoist the 4 rank loads for ILP
    const float ra = ranks[r0 + 0];
    const float rb = ranks[r0 + 1];
    const float rc = ranks[r0 + 2];
    const float rd = ranks[r0 + 3];
    const float rv[4] = {ra, rb, rc, rd};
    #pragma unroll
    for (int rr = 0; rr < 4; ++rr) {
        const float r = rv[rr];
        nfloat4 o;
        o.x = fmaxf(1.0f - fabsf(r - (float)(i + 1)), 0.0f);
        o.y = fmaxf(1.0f - fabsf(r - (float)(i + 2)), 0.0f);
        o.z = fmaxf(1.0f - fabsf(r - (float)(i + 3)), 0.0f);
        o.w = fmaxf(1.0f - fabsf(r - (float)(i + 4)), 0.0f);
        __builtin_nontemporal_store(o,
            reinterpret_cast<nfloat4*>(out + (size_t)(r0 + rr) * N) + threadIdx.x);
    }
}

extern "C" void kernel_launch(void* const* d_in, const int* in_sizes, int n_in,
                              void* d_out, int out_size, void* d_ws, size_t ws_size,
                              hipStream_t stream) {
    const float* x = (const float*)d_in[0];
    float* out = (float*)d_out;
    int*   pos_g = (int*)d_ws;                        // 32K ints  = 128 KB
    float* ranks = (float*)d_ws + BATCH * N;          // 32K floats = 128 KB

    count_kernel<<<BATCH * 8, 256, 0, stream>>>(x, pos_g);
    ranks_kernel<<<BATCH, 256, 0, stream>>>(x, pos_g, ranks);
    fill_kernel<<<(BATCH * N) / 4, 256, 0, stream>>>(ranks, out);
}

// Round 5
// 140.342 us; speedup vs baseline: 1.5952x; 1.0530x over previous
//
#include <hip/hip_runtime.h>
#include <stdint.h>

#define N 1024
#define BATCH 32

// ---------------------------------------------------------------------------
// Kernel A: counting-sort positions. 16 blocks per row, 256 threads each.
//   Each block builds the row's 1024 keys in LDS (redundant, cheap), then
//   counts descending-stable sort positions for its 64 assigned elements.
//   4 threads per element, each covering a 256-key quarter-range.
// ---------------------------------------------------------------------------
__global__ __launch_bounds__(256) void count_kernel(const float* __restrict__ x,
                                                    int* __restrict__ pos_g) {
    __shared__ uint64_t keys[N];      // 8 KB
    __shared__ int      partial[256]; // 1 KB

    const int row   = blockIdx.x >> 4;
    const int chunk = blockIdx.x & 15;
    const int t     = threadIdx.x;

    // ---- build all keys for this row --------------------------------------
    const float4 xq = reinterpret_cast<const float4*>(x + row * N)[t];
    {
        const float vv[4] = {xq.x, xq.y, xq.z, xq.w};
        const int j0 = t << 2;
        #pragma unroll
        for (int e = 0; e < 4; ++e) {
            uint32_t u = __float_as_uint(vv[e]);
            u ^= (u & 0x80000000u) ? 0xFFFFFFFFu : 0x80000000u;  // monotone map
            // descending, stable: position = #{k : key_k > key_j}
            keys[j0 + e] = (((uint64_t)u) << 10) | (uint64_t)(1023 - (j0 + e));
        }
    }
    __syncthreads();

    // ---- count: element e over key quarter [q*256, q*256+256) -------------
    const int e = (chunk << 6) + (t & 63);
    const int q = t >> 6;                    // wave-uniform
    const uint64_t kk = keys[e];
    const int kbeg = q << 8;
    int c = 0;
    #pragma unroll 4
    for (int k = kbeg; k < kbeg + 256; k += 4) {
        c += (int)(keys[k    ] > kk);
        c += (int)(keys[k + 1] > kk);
        c += (int)(keys[k + 2] > kk);
        c += (int)(keys[k + 3] > kk);
    }
    partial[t] = c;
    __syncthreads();

    if (t < 64)
        pos_g[row * N + e] = partial[t] + partial[t + 64] + partial[t + 128] + partial[t + 192];
}

// ---------------------------------------------------------------------------
// Kernel B: per-row soft-rank from positions. One block per row.
//   LDS scatter to sorted order, parallel run-pooling scan, tiny serial PAV
//   over runs, rank emit.
// ---------------------------------------------------------------------------
__global__ __launch_bounds__(256) void ranks_kernel(const float* __restrict__ x,
                                                    const int* __restrict__ pos_g,
                                                    float* __restrict__ ranks) {
    __shared__ float    ss[N];          // sorted values (descending)
    __shared__ float    yv[N];          // y = s + (i - 512)  (centered)
    __shared__ double   csum[N];        // inclusive prefix of yv (double)
    __shared__ int      segid[N];       // run id per sorted position
    __shared__ int      run_start[N+1]; // run boundary positions
    __shared__ float    run_mean[N];    // final (centered) mean per run
    __shared__ double   stk_sum[N];     // PAV stack: block sums
    __shared__ int      stk_cnt[N];     // PAV stack: element counts
    __shared__ int      stk_runs[N];    // PAV stack: runs per block
    __shared__ double   wsumD[4];
    __shared__ int      wsumI[4];

    const int b = blockIdx.x;
    const int t = threadIdx.x;
    const int j0 = t << 2;
    const int lane = t & 63;
    const int wid = t >> 6;

    // ---- load row + positions, scatter into sorted order ------------------
    const float4 xq = reinterpret_cast<const float4*>(x + b * N)[t];
    const int4   pq = reinterpret_cast<const int4*>(pos_g + b * N)[t];
    ss[pq.x] = xq.x; ss[pq.y] = xq.y; ss[pq.z] = xq.z; ss[pq.w] = xq.w;
    __syncthreads();

    // ---- y[i] = s[i] + (i - 512)  (centered for precision) ----------------
    float4 yq;
    {
        const float4 sq = reinterpret_cast<const float4*>(ss)[t];
        yq.x = sq.x + (float)(j0 - 512);
        yq.y = sq.y + (float)(j0 - 511);
        yq.z = sq.z + (float)(j0 - 510);
        yq.w = sq.w + (float)(j0 - 509);
        reinterpret_cast<float4*>(yv)[t] = yq;
    }
    __syncthreads();

    // ---- descent flags + thread-local inclusive scans ---------------------
    const float ye[4] = {yq.x, yq.y, yq.z, yq.w};
    int    fl[4];          // raw flags
    int    lf[4];          // local inclusive flag scan
    double lys[4];         // local inclusive y scan
    {
        float prev = (j0 == 0) ? -1.0e30f : yv[j0 - 1];
        double accy = 0.0; int accf = 0;
        #pragma unroll
        for (int e = 0; e < 4; ++e) {
            const int f = (prev > ye[e]) ? 1 : 0;   // strict descent = run start
            prev = ye[e];
            fl[e] = f;
            accf += f;             lf[e]  = accf;
            accy += (double)ye[e]; lys[e] = accy;
        }
    }
    // ---- wave-level inclusive scan of thread totals -----------------------
    double vy = lys[3]; int vf = lf[3];
    #pragma unroll
    for (int off = 1; off < 64; off <<= 1) {
        const double oy = __shfl_up(vy, off);
        const int    of = __shfl_up(vf, off);
        if (lane >= off) { vy += oy; vf += of; }
    }
    if (lane == 63) { wsumD[wid] = vy; wsumI[wid] = vf; }
    __syncthreads();
    // ---- cross-wave offsets, per-element inclusive values -----------------
    {
        double basey = vy - lys[3]; int basef = vf - lf[3];
        for (int w = 0; w < wid; ++w) { basey += wsumD[w]; basef += wsumI[w]; }
        #pragma unroll
        for (int e = 0; e < 4; ++e) {
            const int p   = j0 + e;
            const int seg = basef + lf[e];
            segid[p] = seg;
            csum[p]  = basey + lys[e];
            if (fl[e]) run_start[seg] = p;   // unique writer per seg >= 1
        }
        if (t == 0) run_start[0] = 0;
    }
    __syncthreads();

    // ---- PAV over runs (thread 0; R is tiny for near-monotone y) ----------
    if (t == 0) {
        const int R = segid[N - 1] + 1;
        run_start[R] = N;
        int sp = 0;
        for (int r = 0; r < R; ++r) {
            const int a   = run_start[r];
            const int bnd = run_start[r + 1];
            double s = csum[bnd - 1] - ((a > 0) ? csum[a - 1] : 0.0);
            int    c = bnd - a;
            int    nr = 1;
            // pool while top block's mean < new block's mean
            while (sp > 0 && s * (double)stk_cnt[sp - 1] > stk_sum[sp - 1] * (double)c) {
                s  += stk_sum[sp - 1];
                c  += stk_cnt[sp - 1];
                nr += stk_runs[sp - 1];
                --sp;
            }
            stk_sum[sp] = s; stk_cnt[sp] = c; stk_runs[sp] = nr; ++sp;
        }
        int rc = 0;
        for (int e2 = 0; e2 < sp; ++e2) {
            const float m = (float)(stk_sum[e2] / (double)stk_cnt[e2]);
            for (int q2 = 0; q2 < stk_runs[e2]; ++q2) run_mean[rc++] = m;
        }
    }
    __syncthreads();

    // ---- ranks[j] = x[j] - (sol - 512) ------------------------------------
    float4 r4;
    r4.x = xq.x - run_mean[segid[pq.x]] + 512.0f;
    r4.y = xq.y - run_mean[segid[pq.y]] + 512.0f;
    r4.z = xq.z - run_mean[segid[pq.z]] + 512.0f;
    r4.w = xq.w - run_mean[segid[pq.w]] + 512.0f;
    reinterpret_cast<float4*>(ranks + b * N)[t] = r4;
}

// ---------------------------------------------------------------------------
// Kernel C: out[b,j,i] = relu(1 - |ranks[b,j] - (i+1)|)
// 4 rows per block; 256 threads x float4 = 1024 elements per row.
// Plain (cached) stores: the harness's own fillBuffer proves this pattern
// sustains ~6.2 TB/s; NT stores are the A/B variable removed this round.
// ---------------------------------------------------------------------------
__global__ __launch_bounds__(256) void fill_kernel(const float* __restrict__ ranks,
                                                   float* __restrict__ out) {
    const int r0 = blockIdx.x << 2;        // first row (b*N + j)
    const int i = threadIdx.x << 2;
    const float ra = ranks[r0 + 0];
    const float rb = ranks[r0 + 1];
    const float rc = ranks[r0 + 2];
    const float rd = ranks[r0 + 3];
    const float rv[4] = {ra, rb, rc, rd};
    #pragma unroll
    for (int rr = 0; rr < 4; ++rr) {
        const float r = rv[rr];
        float4 o;
        o.x = fmaxf(1.0f - fabsf(r - (float)(i + 1)), 0.0f);
        o.y = fmaxf(1.0f - fabsf(r - (float)(i + 2)), 0.0f);
        o.z = fmaxf(1.0f - fabsf(r - (float)(i + 3)), 0.0f);
        o.w = fmaxf(1.0f - fabsf(r - (float)(i + 4)), 0.0f);
        reinterpret_cast<float4*>(out + (size_t)(r0 + rr) * N)[threadIdx.x] = o;
    }
}

extern "C" void kernel_launch(void* const* d_in, const int* in_sizes, int n_in,
                              void* d_out, int out_size, void* d_ws, size_t ws_size,
                              hipStream_t stream) {
    const float* x = (const float*)d_in[0];
    float* out = (float*)d_out;
    int*   pos_g = (int*)d_ws;                        // 32K ints  = 128 KB
    float* ranks = (float*)d_ws + BATCH * N;          // 32K floats = 128 KB

    count_kernel<<<BATCH * 16, 256, 0, stream>>>(x, pos_g);
    ranks_kernel<<<BATCH, 256, 0, stream>>>(x, pos_g, ranks);
    fill_kernel<<<(BATCH * N) / 4, 256, 0, stream>>>(ranks, out);
}